// Round 10
// baseline (119.564 us; speedup 1.0000x reference)
//
#include <hip/hip_runtime.h>

// Problem constants
#define BB    32
#define NF    500
#define FRAME 160
#define OV    40
#define KK    16
#define NS    (NF * FRAME)     // 80000
#define FEAT  256

#define NBODY2 (BB * NF * 15)   // 240000 threads: t in [40,160), both couts
#define NOV2   (BB * NF * 5)    //  80000 threads: t in [0,40),   both couts

// gain_a = (6+6)/2 * ln10/20 ; shape_gain = 10^(-6/20)
__device__ const float GAIN_A     = 0.6907755278982137f;
__device__ const float SHAPE_GAIN = 0.5011872336272722f;

// ---------------------------------------------------------------------------
// wcalc6: filter build. Grid (8 f-tiles, 32 b, 2 cout), block 512 = 8 waves.
// Lane l = frame f0+l; wave w owns rows z*32 + w*4 .. +3.
//  - feat chunk in LDS, float4-swizzled -> 2 conflict-free ds_read_b128 per
//    8-k step. THE ONLY LDS TRAFFIC IN THE LOOP.
//  - w rows + gain row are wave-uniform -> read straight from global through
//    the SCALAR path (s_load_dwordx8, v_fmac_f32 with SGPR operand). ckw is
//    64 KB, L2-resident; unroll 2 keeps ~2 steps of s_loads in flight.
//  - launch_bounds(512,4): VGPR cap 128. R4's failure was VGPR_Count=28
//    (occupancy-greedy regalloc) -> zero ILP; this is the fix.
// ---------------------------------------------------------------------------
__global__ __launch_bounds__(512, 4) void wcalc6_kernel(
    const float* __restrict__ feats,  // (B, NF, 256)
    const float* __restrict__ ckw,    // (64, 256)
    const float* __restrict__ ckb,    // (64,)
    const float* __restrict__ fgw,    // (2, 256)
    const float* __restrict__ fgb,    // (2,)
    float* __restrict__ wout)         // (B*NF, 64)
{
    int tile = blockIdx.x;            // 0..7
    int b    = blockIdx.y;            // 0..31
    int z    = blockIdx.z;            // cout 0/1
    int f0   = tile * 64;
    int tid  = threadIdx.x;
    int w    = tid >> 6;              // 0..7
    int l    = tid & 63;              // frame offset

    __shared__ float sf[64 * 128];    // 32 KB feats chunk, swizzled
    __shared__ float sr[8][64];       // ssq partials

    int rbase = __builtin_amdgcn_readfirstlane(z * 32 + w * 4);
    const float* gw0 = fgw + z * FEAT;

    float acc[4] = {0.f, 0.f, 0.f, 0.f};
    float g = 0.f;

    for (int h = 0; h < 2; ++h) {     // two 128-feat chunks
        __syncthreads();              // previous chunk's readers done
        #pragma unroll
        for (int p = 0; p < 4; ++p) {
            int F  = p * 512 + tid;   // 0..2047 float4 slots
            int fr = F >> 5;          // frame row 0..63
            int c4 = F & 31;          // float4 col
            int f  = f0 + fr;
            float4 v = make_float4(0.f, 0.f, 0.f, 0.f);
            if (f < NF)
                v = *(const float4*)(feats + ((size_t)(b * NF + f)) * FEAT
                                     + h * 128 + c4 * 4);
            *(float4*)(sf + fr * 128 + ((c4 ^ (fr & 7)) * 4)) = v;
        }
        __syncthreads();

        #pragma unroll 2
        for (int cl = 0; cl < 16; ++cl) {
            float4 fa = *(const float4*)(sf + l * 128 + (((2 * cl)     ^ (l & 7)) * 4));
            float4 fb = *(const float4*)(sf + l * 128 + (((2 * cl + 1) ^ (l & 7)) * 4));
            float fr8[8] = {fa.x, fa.y, fa.z, fa.w, fb.x, fb.y, fb.z, fb.w};
            int kg = h * 128 + cl * 8;
            #pragma unroll
            for (int r = 0; r < 4; ++r) {
                const float* wp = ckw + (size_t)(rbase + r) * FEAT + kg;  // scalar
                #pragma unroll
                for (int i = 0; i < 8; ++i)
                    acc[r] = fmaf(fr8[i], wp[i], acc[r]);
            }
            const float* gp = gw0 + kg;                                    // scalar
            #pragma unroll
            for (int i = 0; i < 8; ++i)
                g = fmaf(fr8[i], gp[i], g);
        }
    }

    #pragma unroll
    for (int r = 0; r < 4; ++r) acc[r] += ckb[rbase + r];
    g += fgb[z];

    float ssq = 0.f;
    #pragma unroll
    for (int r = 0; r < 4; ++r) ssq = fmaf(acc[r], acc[r], ssq);
    sr[w][l] = ssq;
    __syncthreads();
    float tot = 0.f;
    #pragma unroll
    for (int j = 0; j < 8; ++j) tot += sr[j][l];
    float norm = 1e-6f + sqrtf(tot);

    float gain = expf(GAIN_A * tanhf(g));
    float sc   = gain * SHAPE_GAIN / norm;
    float idv  = gain * (1.0f - SHAPE_GAIN);

    int f = f0 + l;
    if (f < NF) {
        float o[4];
        #pragma unroll
        for (int r = 0; r < 4; ++r)
            o[r] = acc[r] * sc + ((((rbase + r) & 15) == 7) ? idv : 0.f);
        float4 v;
        v.x = o[0]; v.y = o[1]; v.z = o[2]; v.w = o[3];
        *(float4*)(wout + ((size_t)(b * NF + f)) * 64 + rbase) = v;
    }
}

// ---------------------------------------------------------------------------
// conv: direct conv + overlap-add. Each thread: 8 samples x BOTH couts.
// Region split: [0, NBODY2) body t in [40,160); [NBODY2, +NOV2) overlap.
// UNCHANGED (one variable per round).
// ---------------------------------------------------------------------------
__global__ __launch_bounds__(256) void conv2_kernel(
    const float* __restrict__ x,     // (B, 2, NS)
    const float* __restrict__ w,     // (B*NF, 64)
    const float* __restrict__ owin,  // (40,)
    float* __restrict__ out)         // (B, 2, NS)
{
    int flat = blockIdx.x * 256 + threadIdx.x;   // 0 .. 319999
    if (flat < NBODY2) {
        int g    = flat % 15;
        int rest = flat / 15;
        int f    = rest % NF;
        int b    = rest / NF;
        int s0   = f * FRAME + OV + g * 8;       // >= 40: no underflow

        const float* xb = x + (size_t)b * 2 * NS;
        float xr[2][24];
        #pragma unroll
        for (int ci = 0; ci < 2; ++ci) {
            const float* xc = xb + (size_t)ci * NS + s0 - 16;
            #pragma unroll
            for (int c = 0; c < 6; ++c) {
                float4 v = *(const float4*)(xc + c * 4);
                xr[ci][c * 4 + 0] = v.x; xr[ci][c * 4 + 1] = v.y;
                xr[ci][c * 4 + 2] = v.z; xr[ci][c * 4 + 3] = v.w;
            }
        }
        const float* wfb = w + (size_t)(b * NF + f) * 64;
        #pragma unroll
        for (int cout = 0; cout < 2; ++cout) {
            const float4* wf = (const float4*)(wfb + cout * 32);
            float wr[32];
            #pragma unroll
            for (int q = 0; q < 8; ++q) {
                float4 v = wf[q];
                wr[q * 4 + 0] = v.x; wr[q * 4 + 1] = v.y;
                wr[q * 4 + 2] = v.z; wr[q * 4 + 3] = v.w;
            }
            float acc[8];
            #pragma unroll
            for (int j = 0; j < 8; ++j) acc[j] = 0.f;
            #pragma unroll
            for (int ci = 0; ci < 2; ++ci)
                #pragma unroll
                for (int k = 0; k < KK; ++k) {
                    float wk = wr[ci * 16 + k];
                    #pragma unroll
                    for (int j = 0; j < 8; ++j)
                        acc[j] = fmaf(wk, xr[ci][16 + j - k], acc[j]);
                }
            float* dst = out + (size_t)(b * 2 + cout) * NS + s0;
            float4 v0, v1;
            v0.x = acc[0]; v0.y = acc[1]; v0.z = acc[2]; v0.w = acc[3];
            v1.x = acc[4]; v1.y = acc[5]; v1.z = acc[6]; v1.w = acc[7];
            *(float4*)(dst)     = v0;
            *(float4*)(dst + 4) = v1;
        }
    } else {
        int flat2 = flat - NBODY2;
        int g    = flat2 % 5;
        int rest = flat2 / 5;
        int f    = rest % NF;
        int b    = rest / NF;
        int t0   = g * 8;
        int s0   = f * FRAME + t0;

        const float* xb = x + (size_t)b * 2 * NS;
        float xr[2][24];
        #pragma unroll
        for (int ci = 0; ci < 2; ++ci) {
            const float* xc = xb + (size_t)ci * NS + s0 - 16;
            #pragma unroll
            for (int c = 0; c < 6; ++c) {
                if (s0 - 16 + c * 4 >= 0) {
                    float4 v = *(const float4*)(xc + c * 4);
                    xr[ci][c * 4 + 0] = v.x; xr[ci][c * 4 + 1] = v.y;
                    xr[ci][c * 4 + 2] = v.z; xr[ci][c * 4 + 3] = v.w;
                } else {
                    xr[ci][c * 4 + 0] = 0.f; xr[ci][c * 4 + 1] = 0.f;
                    xr[ci][c * 4 + 2] = 0.f; xr[ci][c * 4 + 3] = 0.f;
                }
            }
        }

        // owin windows: o_tail[j] = owin[t0+j], o_head[j] = owin[39-t0-j]
        float o_tail[8], o_head[8];
        {
            float4 a = *(const float4*)(owin + t0);
            float4 c = *(const float4*)(owin + t0 + 4);
            o_tail[0] = a.x; o_tail[1] = a.y; o_tail[2] = a.z; o_tail[3] = a.w;
            o_tail[4] = c.x; o_tail[5] = c.y; o_tail[6] = c.z; o_tail[7] = c.w;
            float4 d = *(const float4*)(owin + (32 - t0));
            float4 e = *(const float4*)(owin + (36 - t0));
            o_head[0] = e.w; o_head[1] = e.z; o_head[2] = e.y; o_head[3] = e.x;
            o_head[4] = d.w; o_head[5] = d.z; o_head[6] = d.y; o_head[7] = d.x;
        }

        const float* wfb = w + (size_t)(b * NF + f) * 64;
        #pragma unroll
        for (int cout = 0; cout < 2; ++cout) {
            float res[8];
            #pragma unroll
            for (int j = 0; j < 8; ++j) res[j] = 0.f;

            float wr[32];
            if (f > 0) {   // previous frame's filter (tail contribution)
                const float4* wp = (const float4*)(wfb - 64 + cout * 32);
                #pragma unroll
                for (int q = 0; q < 8; ++q) {
                    float4 v = wp[q];
                    wr[q * 4 + 0] = v.x; wr[q * 4 + 1] = v.y;
                    wr[q * 4 + 2] = v.z; wr[q * 4 + 3] = v.w;
                }
                float acc[8];
                #pragma unroll
                for (int j = 0; j < 8; ++j) acc[j] = 0.f;
                #pragma unroll
                for (int ci = 0; ci < 2; ++ci)
                    #pragma unroll
                    for (int k = 0; k < KK; ++k) {
                        float wk = wr[ci * 16 + k];
                        #pragma unroll
                        for (int j = 0; j < 8; ++j)
                            acc[j] = fmaf(wk, xr[ci][16 + j - k], acc[j]);
                    }
                #pragma unroll
                for (int j = 0; j < 8; ++j) res[j] = o_tail[j] * acc[j];
            }
            {
                const float4* wf = (const float4*)(wfb + cout * 32);
                #pragma unroll
                for (int q = 0; q < 8; ++q) {
                    float4 v = wf[q];
                    wr[q * 4 + 0] = v.x; wr[q * 4 + 1] = v.y;
                    wr[q * 4 + 2] = v.z; wr[q * 4 + 3] = v.w;
                }
                float acc[8];
                #pragma unroll
                for (int j = 0; j < 8; ++j) acc[j] = 0.f;
                #pragma unroll
                for (int ci = 0; ci < 2; ++ci)
                    #pragma unroll
                    for (int k = 0; k < KK; ++k) {
                        float wk = wr[ci * 16 + k];
                        #pragma unroll
                        for (int j = 0; j < 8; ++j)
                            acc[j] = fmaf(wk, xr[ci][16 + j - k], acc[j]);
                    }
                #pragma unroll
                for (int j = 0; j < 8; ++j)
                    res[j] = fmaf(o_head[j], acc[j], res[j]);
            }
            float* dst = out + (size_t)(b * 2 + cout) * NS + s0;
            float4 v0, v1;
            v0.x = res[0]; v0.y = res[1]; v0.z = res[2]; v0.w = res[3];
            v1.x = res[4]; v1.y = res[5]; v1.z = res[6]; v1.w = res[7];
            *(float4*)(dst)     = v0;
            *(float4*)(dst + 4) = v1;
        }
    }
}

extern "C" void kernel_launch(void* const* d_in, const int* in_sizes, int n_in,
                              void* d_out, int out_size, void* d_ws, size_t ws_size,
                              hipStream_t stream) {
    const float* x     = (const float*)d_in[0];
    const float* feats = (const float*)d_in[1];
    const float* ckw   = (const float*)d_in[2];
    const float* ckb   = (const float*)d_in[3];
    const float* fgw   = (const float*)d_in[4];
    const float* fgb   = (const float*)d_in[5];
    const float* owin  = (const float*)d_in[6];
    float* out  = (float*)d_out;
    float* wbuf = (float*)d_ws;                 // B*NF*64*4 = 4.1 MB

    hipLaunchKernelGGL(wcalc6_kernel, dim3(8, BB, 2), dim3(512), 0, stream,
                       feats, ckw, ckb, fgw, fgb, wbuf);

    hipLaunchKernelGGL(conv2_kernel, dim3((NBODY2 + NOV2) / 256), dim3(256), 0, stream,
                       x, wbuf, owin, out);
}